// Round 4
// baseline (137.176 us; speedup 1.0000x reference)
//
#include <hip/hip_runtime.h>
#include <hip/hip_fp16.h>

// SSIM loss, fused, MFMA-blur v4. fp32 in [16,3,512,512], fp32 scalar out.
// v3 failed verification (absmax 1.05, likely nondeterministic). v4 keeps
// v3's core win (h-blur A-fragments built in registers -> no plane LDS
// buffer, 28.7KB LDS -> 5 blocks/CU) but reverts every other v3 delta to
// the v2-verified pattern:
//  - fp32 u/v math then convert (bitwise = v2's ewise)
//  - prologue: full hstore(gen-2,0) / sync / hstore(gen-1,12) overwrite
//    pattern (v2's), no lane-masked single-region trick
//  - TWO barriers per step; hstore and vblur in SEPARATE regions -> zero
//    ring read/write concurrency (stricter than v2)
// MFMA blurs (v_mfma_f32_16x16x32_f16, fp32 accum):
//   h: D[r][c] = sum_k plane[r][16wv+k] * w[k-c-3]   (A from regs)
//   v: D[c][r] = sum_k ring[c][16j+k]   * w[k-r]
// Ring col-major [4][64][56] halves; b64 writes / b128 reads both bank-
// balanced (4/bank resp. 8/bank = minimum). fp16 weight-sum drift folded
// into scaled C1/C2 (num/den invariant under accumulator scaling).

#define WIDTH  512
#define HEIGHT 512
#define TW 64
#define SH 128
#define RING 48                  // logical ring rows (mod-48)
#define RST 56                   // physical slot stride (bank dispersion)
#define TILES_X 8
#define TILES_Y (HEIGHT / SH)    // 4
#define PLANES 48
#define NBLK (TILES_X * TILES_Y * PLANES)   // 1536
#define NPIXF 12582912.0f

typedef _Float16 half8_t __attribute__((ext_vector_type(8)));
typedef float f32x4_t __attribute__((ext_vector_type(4)));
typedef unsigned int u32x4_t __attribute__((ext_vector_type(4)));

// banded weight lookup; 0 outside [0,10]. Symmetric kernel.
__device__ __forceinline__ float wsel(int i) {
    unsigned a = (unsigned)i;
    float r = 0.f;
    if (a == 5u)              r = 0.26601168f;
    if (a == 4u || a == 6u)   r = 0.21300566f;
    if (a == 3u || a == 7u)   r = 0.10936069f;
    if (a == 2u || a == 8u)   r = 0.03600077f;
    if (a == 1u || a == 9u)   r = 0.00759881f;
    if (a == 0u || a == 10u)  r = 0.00102839f;
    return r;
}

__device__ __forceinline__ unsigned cvt2(float a, float b) {
    return __builtin_bit_cast(unsigned, __floats2half2_rn(a, b));
}

__global__ __launch_bounds__(256, 4)
void ssim_main(const float* __restrict__ pred,
               const float* __restrict__ tgt,
               float* __restrict__ partial) {
    __shared__ __align__(16) __half s_ring[4][TW][RST];   // 28672 B col-major
    __shared__ float s_red[4];

    const int tid  = threadIdx.x;
    const int wv   = tid >> 6;          // wave id = 16-col output chunk
    const int lane = tid & 63;
    const int r15  = lane & 15;
    const int g4   = lane >> 4;
    const int x0 = blockIdx.x * TW;
    const int y0 = blockIdx.y * SH;
    const size_t plane_off = (size_t)blockIdx.z * (WIDTH * HEIGHT);
    const float* P = pred + plane_off;
    const float* T = tgt + plane_off;

    // this thread's fragment window: global x base (multiple of 8)
    const int gxb  = x0 - 8 + (wv << 4) + (g4 << 3);
    const int colA = (wv << 4) + r15;                  // ring column

    // fp16 weight-sum per pass (compile-time): acc scale a = s1^2.
    const float s1 = 2.f * ((float)(_Float16)0.00102839f + (float)(_Float16)0.00759881f
                   + (float)(_Float16)0.03600077f + (float)(_Float16)0.10936069f
                   + (float)(_Float16)0.21300566f) + (float)(_Float16)0.26601168f;
    const float a   = s1 * s1;
    const float C1A = a * a * 1e-4f;
    const float C2A = a * a * 9e-4f;

    // Banded weight fragments (B operand: col = lane&15, k = (lane>>4)*8+j).
    half8_t Bh, Bv;
#pragma unroll
    for (int jj = 0; jj < 8; ++jj) {
        int k = g4 * 8 + jj;
        Bv[jj] = (_Float16)wsel(k - r15);        // Wv[k][r] = w[k-r]
        Bh[jj] = (_Float16)wsel(k - r15 - 3);    // Wh[k][c] = w[k-c-3]
    }

    // ---- raw loads: 8 px at row gybase+r15, cols gxb..gxb+7 (clamped) ----
    auto load8 = [&](int gybase, float4& p0, float4& p1,
                     float4& t0, float4& t1) {
        int gy = gybase + r15;
        if (gy < 0) gy = 0;
        if (gy > HEIGHT - 1) gy = HEIGHT - 1;
        int gxc = gxb;
        if (gxc < 0) gxc = 0;
        if (gxc > WIDTH - 8) gxc = WIDTH - 8;
        const float* pr = P + ((size_t)gy << 9) + gxc;
        const float* tr = T + ((size_t)gy << 9) + gxc;
        p0 = *(const float4*)pr; p1 = *(const float4*)(pr + 4);
        t0 = *(const float4*)tr; t1 = *(const float4*)(tr + 4);
    };

    // ---- ewise in regs: build 4 A-fragments (p,t,u,v), fp32 math (=v2) ----
    // 8-aligned windows + WIDTH mult of 8: windows are all-in or all-out,
    // so masking is one bool per fragment.
    auto make_frags = [&](int gybase, float4 pv0, float4 pv1,
                          float4 tv0, float4 tv1, u32x4_t* F) {
        int gy = gybase + r15;
        const bool ok = ((unsigned)gy < (unsigned)HEIGHT) &&
                        ((unsigned)gxb <= (unsigned)(WIDTH - 8));
        if (!ok) {
            pv0.x = pv0.y = pv0.z = pv0.w = 0.f;
            pv1.x = pv1.y = pv1.z = pv1.w = 0.f;
            tv0.x = tv0.y = tv0.z = tv0.w = 0.f;
            tv1.x = tv1.y = tv1.z = tv1.w = 0.f;
        }
        float u0 = fmaf(pv0.x, pv0.x, tv0.x * tv0.x), v0 = pv0.x * tv0.x;
        float u1 = fmaf(pv0.y, pv0.y, tv0.y * tv0.y), v1 = pv0.y * tv0.y;
        float u2 = fmaf(pv0.z, pv0.z, tv0.z * tv0.z), v2 = pv0.z * tv0.z;
        float u3 = fmaf(pv0.w, pv0.w, tv0.w * tv0.w), v3 = pv0.w * tv0.w;
        float u4 = fmaf(pv1.x, pv1.x, tv1.x * tv1.x), v4 = pv1.x * tv1.x;
        float u5 = fmaf(pv1.y, pv1.y, tv1.y * tv1.y), v5 = pv1.y * tv1.y;
        float u6 = fmaf(pv1.z, pv1.z, tv1.z * tv1.z), v6 = pv1.z * tv1.z;
        float u7 = fmaf(pv1.w, pv1.w, tv1.w * tv1.w), v7 = pv1.w * tv1.w;
        u32x4_t Pu, Tu, Uu, Vu;
        Pu[0] = cvt2(pv0.x, pv0.y); Pu[1] = cvt2(pv0.z, pv0.w);
        Pu[2] = cvt2(pv1.x, pv1.y); Pu[3] = cvt2(pv1.z, pv1.w);
        Tu[0] = cvt2(tv0.x, tv0.y); Tu[1] = cvt2(tv0.z, tv0.w);
        Tu[2] = cvt2(tv1.x, tv1.y); Tu[3] = cvt2(tv1.z, tv1.w);
        Uu[0] = cvt2(u0, u1); Uu[1] = cvt2(u2, u3);
        Uu[2] = cvt2(u4, u5); Uu[3] = cvt2(u6, u7);
        Vu[0] = cvt2(v0, v1); Vu[1] = cvt2(v2, v3);
        Vu[2] = cvt2(v4, v5); Vu[3] = cvt2(v6, v7);
        F[0] = Pu; F[1] = Tu; F[2] = Uu; F[3] = Vu;
    };

    // ---- h-blur MFMA from register fragments; pack D rows to uint2 ----
    auto hcompute = [&](const u32x4_t* F, uint2* dpk) {
#pragma unroll
        for (int q = 0; q < 4; ++q) {
            f32x4_t z = {0.f, 0.f, 0.f, 0.f};
            f32x4_t d = __builtin_amdgcn_mfma_f32_16x16x32_f16(
                __builtin_bit_cast(half8_t, F[q]), Bh, z, 0, 0, 0);
            dpk[q].x = cvt2(d[0], d[1]);
            dpk[q].y = cvt2(d[2], d[3]);
        }
    };
    // lane's 4 D rows (slots s0..s0+3, s0 mult of 4) = one 8B ds_write_b64
    auto hstore = [&](const uint2* dpk, int relbase) {
        int s0 = relbase + 4 * g4;
        if (s0 >= 96) s0 -= 96; else if (s0 >= 48) s0 -= 48;
#pragma unroll
        for (int q = 0; q < 4; ++q)
            *(uint2*)&s_ring[q][colA][s0] = dpk[q];
    };

    float lsum = 0.f;

    // ---- v-blur MFMA + SSIM. Reads rel 16j..16j+31 (k>=26 zero-weight;
    // all slots finite: zero-init or prior-gen data). ----
    auto vblur = [&](int jstep) {
        int sg = 16 * jstep + (g4 << 3);
        if (sg >= 96) sg -= 96; else if (sg >= 48) sg -= 48;
        f32x4_t acc[4];
#pragma unroll
        for (int q = 0; q < 4; ++q) {
            u32x4_t ra = *(const u32x4_t*)&s_ring[q][colA][sg];
            f32x4_t z = {0.f, 0.f, 0.f, 0.f};
            acc[q] = __builtin_amdgcn_mfma_f32_16x16x32_f16(
                __builtin_bit_cast(half8_t, ra), Bv, z, 0, 0, 0);
        }
#pragma unroll
        for (int r = 0; r < 4; ++r) {
            float mp = acc[0][r], mt = acc[1][r];       // scaled by a
            float U  = acc[2][r], V  = acc[3][r];
            float mpt  = mp * mt;                        // a^2 * true
            float B2   = fmaf(mp, mp, mt * mt);          // a^2 * true
            float S    = fmaf(a, V, -mpt);               // a^2 * sigma_pt
            float Ssum = fmaf(a, U, -B2);                // a^2 * (sp+st)
            float num = fmaf(2.f, mpt, C1A) * fmaf(2.f, S, C2A);
            float den = (B2 + C1A) * (Ssum + C2A);
            lsum += __fdividef(num, den);
        }
    };

    // ---- Prologue (v2 store pattern: barrier-separated overwrite) ----
    float4 rp0, rp1, rt0, rt1;      // loop-carried raw set
    float4 sp0, sp1, st0, st1;      // prologue-only second set
    load8(y0 - 5, rp0, rp1, rt0, rt1);    // gen -2: rel 0..15
    load8(y0 + 7, sp0, sp1, st0, st1);    // gen -1: rel 12..27
    {
        u32x4_t z4 = {0u, 0u, 0u, 0u};
#pragma unroll
        for (int i = 0; i < 7; ++i)
            ((u32x4_t*)s_ring)[tid + 256 * i] = z4;   // finite pads everywhere
    }
    u32x4_t F2[4], F1[4];
    uint2 d2[4], d1[4];
    make_frags(y0 - 5, rp0, rp1, rt0, rt1, F2);
    hcompute(F2, d2);
    make_frags(y0 + 7, sp0, sp1, st0, st1, F1);
    hcompute(F1, d1);
    load8(y0 + 23, rp0, rp1, rt0, rt1);   // gen 0 raw
    __syncthreads();                       // zero-init visible
    hstore(d2, 0);                         // rel 0..15 (full)
    __syncthreads();
    hstore(d1, 12);                        // rel 12..27 (12..15 same data)
    __syncthreads();                       // ring ready for step 0

    // ---- Main loop: 8 steps x 16 output rows, two regions per step ----
#pragma unroll 1
    for (int j = 0; j < 8; ++j) {
        u32x4_t F[4];
        uint2 dpk[4];
        // region 1: pure-register h-blur for gen j + vblur(j) ring reads
        if (j < 7) {
            make_frags(y0 + 16 * j + 23, rp0, rp1, rt0, rt1, F);
            hcompute(F, dpk);
        }
        vblur(j);                          // reads rel 16j..16j+25 (+pads)
        __syncthreads();
        // region 2: ring writes for gen j + next raw loads (no reads here)
        if (j < 7) hstore(dpk, 16 * j + 28);   // rel 16j+28..43
        if (j < 6) load8(y0 + 16 * (j + 1) + 23, rp0, rp1, rt0, rt1);
        __syncthreads();
    }

    // ---- Block reduction -> one partial per block ----
#pragma unroll
    for (int off = 32; off > 0; off >>= 1) lsum += __shfl_down(lsum, off);
    if ((tid & 63) == 0) s_red[tid >> 6] = lsum;
    __syncthreads();
    if (tid == 0) {
        partial[(blockIdx.z * TILES_Y + blockIdx.y) * TILES_X + blockIdx.x] =
            s_red[0] + s_red[1] + s_red[2] + s_red[3];
    }
}

__global__ __launch_bounds__(256)
void ssim_final(const float* __restrict__ partial, float* __restrict__ out) {
    __shared__ float s_red[4];
    float s = 0.f;
    for (int i = threadIdx.x; i < NBLK; i += 256) s += partial[i];
#pragma unroll
    for (int off = 32; off > 0; off >>= 1) s += __shfl_down(s, off);
    if ((threadIdx.x & 63) == 0) s_red[threadIdx.x >> 6] = s;
    __syncthreads();
    if (threadIdx.x == 0) {
        float total = s_red[0] + s_red[1] + s_red[2] + s_red[3];
        out[0] = 1.0f - total / NPIXF;
    }
}

extern "C" void kernel_launch(void* const* d_in, const int* in_sizes, int n_in,
                              void* d_out, int out_size, void* d_ws, size_t ws_size,
                              hipStream_t stream) {
    const float* pred = (const float*)d_in[0];
    const float* tgt  = (const float*)d_in[1];
    float* partial = (float*)d_ws;   // NBLK floats, fully rewritten each call

    dim3 grid(TILES_X, TILES_Y, PLANES);
    ssim_main<<<grid, dim3(256), 0, stream>>>(pred, tgt, partial);
    ssim_final<<<1, dim3(256), 0, stream>>>(partial, (float*)d_out);
}

// Round 5
// 136.556 us; speedup vs baseline: 1.0045x; 1.0045x over previous
//
#include <hip/hip_runtime.h>
#include <hip/hip_fp16.h>

// SSIM loss, fused, MFMA-blur v5. fp32 in [16,3,512,512], fp32 scalar out.
// Round-4 postmortem: 47.5us, VALU 35%, MFMA 5%, HBM 27% -> nothing busy;
// barrier-drain (vmcnt(0) before s_barrier) serializes load latency into
// every step. KEY INSIGHT: all ring accesses use column 16wv+r15 -> the
// ring is WAVE-PRIVATE. h-blur A-frags come from the thread's own loads,
// B operands are registers => the main loop has ZERO cross-wave dataflow.
// v5 deletes ALL barriers except the final reduction one; waves slide
// freely and latency is hidden by TLP. Zero-init is per-wave (own 16
// columns); load8(j+1) issued right after make_frags(j) frees the regs,
// covered by hcompute+hstore+vblur. Arithmetic bitwise = v4 (verified).
// MFMA blurs (v_mfma_f32_16x16x32_f16, fp32 accum):
//   h: D[r][c] = sum_k plane[r][16wv+k] * w[k-c-3]   (A from regs)
//   v: D[c][r] = sum_k ring[c][16j+k]   * w[k-r]
// Ring col-major [4][64][56]; b64 writes / b128 reads bank-balanced.
// fp16 weight-sum drift folded into scaled C1/C2.

#define WIDTH  512
#define HEIGHT 512
#define TW 64
#define SH 128
#define RING 48                  // logical ring rows (mod-48)
#define RST 56                   // physical slot stride (bank dispersion)
#define TILES_X 8
#define TILES_Y (HEIGHT / SH)    // 4
#define PLANES 48
#define NBLK (TILES_X * TILES_Y * PLANES)   // 1536
#define NPIXF 12582912.0f

typedef _Float16 half8_t __attribute__((ext_vector_type(8)));
typedef float f32x4_t __attribute__((ext_vector_type(4)));
typedef unsigned int u32x4_t __attribute__((ext_vector_type(4)));

// banded weight lookup; 0 outside [0,10]. Symmetric kernel.
__device__ __forceinline__ float wsel(int i) {
    unsigned a = (unsigned)i;
    float r = 0.f;
    if (a == 5u)              r = 0.26601168f;
    if (a == 4u || a == 6u)   r = 0.21300566f;
    if (a == 3u || a == 7u)   r = 0.10936069f;
    if (a == 2u || a == 8u)   r = 0.03600077f;
    if (a == 1u || a == 9u)   r = 0.00759881f;
    if (a == 0u || a == 10u)  r = 0.00102839f;
    return r;
}

__device__ __forceinline__ unsigned cvt2(float a, float b) {
    return __builtin_bit_cast(unsigned, __floats2half2_rn(a, b));
}

__global__ __launch_bounds__(256, 4)
void ssim_main(const float* __restrict__ pred,
               const float* __restrict__ tgt,
               float* __restrict__ partial) {
    __shared__ __align__(16) __half s_ring[4][TW][RST];   // 28672 B col-major
    __shared__ float s_red[4];

    const int tid  = threadIdx.x;
    const int wv   = tid >> 6;          // wave id = 16-col output chunk
    const int lane = tid & 63;
    const int r15  = lane & 15;
    const int g4   = lane >> 4;
    const int x0 = blockIdx.x * TW;
    const int y0 = blockIdx.y * SH;
    const size_t plane_off = (size_t)blockIdx.z * (WIDTH * HEIGHT);
    const float* P = pred + plane_off;
    const float* T = tgt + plane_off;

    // this thread's fragment window: global x base (multiple of 8)
    const int gxb  = x0 - 8 + (wv << 4) + (g4 << 3);
    const int colA = (wv << 4) + r15;                  // ring column (wave-private)

    // fp16 weight-sum per pass (compile-time): acc scale a = s1^2.
    const float s1 = 2.f * ((float)(_Float16)0.00102839f + (float)(_Float16)0.00759881f
                   + (float)(_Float16)0.03600077f + (float)(_Float16)0.10936069f
                   + (float)(_Float16)0.21300566f) + (float)(_Float16)0.26601168f;
    const float a   = s1 * s1;
    const float C1A = a * a * 1e-4f;
    const float C2A = a * a * 9e-4f;

    // Banded weight fragments (B operand: col = lane&15, k = (lane>>4)*8+j).
    half8_t Bh, Bv;
#pragma unroll
    for (int jj = 0; jj < 8; ++jj) {
        int k = g4 * 8 + jj;
        Bv[jj] = (_Float16)wsel(k - r15);        // Wv[k][r] = w[k-r]
        Bh[jj] = (_Float16)wsel(k - r15 - 3);    // Wh[k][c] = w[k-c-3]
    }

    // ---- raw loads: 8 px at row gybase+r15, cols gxb..gxb+7 (clamped) ----
    auto load8 = [&](int gybase, float4& p0, float4& p1,
                     float4& t0, float4& t1) {
        int gy = gybase + r15;
        if (gy < 0) gy = 0;
        if (gy > HEIGHT - 1) gy = HEIGHT - 1;
        int gxc = gxb;
        if (gxc < 0) gxc = 0;
        if (gxc > WIDTH - 8) gxc = WIDTH - 8;
        const float* pr = P + ((size_t)gy << 9) + gxc;
        const float* tr = T + ((size_t)gy << 9) + gxc;
        p0 = *(const float4*)pr; p1 = *(const float4*)(pr + 4);
        t0 = *(const float4*)tr; t1 = *(const float4*)(tr + 4);
    };

    // ---- ewise in regs: build 4 A-fragments (p,t,u,v), fp32 math ----
    auto make_frags = [&](int gybase, float4 pv0, float4 pv1,
                          float4 tv0, float4 tv1, u32x4_t* F) {
        int gy = gybase + r15;
        const bool ok = ((unsigned)gy < (unsigned)HEIGHT) &&
                        ((unsigned)gxb <= (unsigned)(WIDTH - 8));
        if (!ok) {
            pv0.x = pv0.y = pv0.z = pv0.w = 0.f;
            pv1.x = pv1.y = pv1.z = pv1.w = 0.f;
            tv0.x = tv0.y = tv0.z = tv0.w = 0.f;
            tv1.x = tv1.y = tv1.z = tv1.w = 0.f;
        }
        float u0 = fmaf(pv0.x, pv0.x, tv0.x * tv0.x), v0 = pv0.x * tv0.x;
        float u1 = fmaf(pv0.y, pv0.y, tv0.y * tv0.y), v1 = pv0.y * tv0.y;
        float u2 = fmaf(pv0.z, pv0.z, tv0.z * tv0.z), v2 = pv0.z * tv0.z;
        float u3 = fmaf(pv0.w, pv0.w, tv0.w * tv0.w), v3 = pv0.w * tv0.w;
        float u4 = fmaf(pv1.x, pv1.x, tv1.x * tv1.x), v4 = pv1.x * tv1.x;
        float u5 = fmaf(pv1.y, pv1.y, tv1.y * tv1.y), v5 = pv1.y * tv1.y;
        float u6 = fmaf(pv1.z, pv1.z, tv1.z * tv1.z), v6 = pv1.z * tv1.z;
        float u7 = fmaf(pv1.w, pv1.w, tv1.w * tv1.w), v7 = pv1.w * tv1.w;
        u32x4_t Pu, Tu, Uu, Vu;
        Pu[0] = cvt2(pv0.x, pv0.y); Pu[1] = cvt2(pv0.z, pv0.w);
        Pu[2] = cvt2(pv1.x, pv1.y); Pu[3] = cvt2(pv1.z, pv1.w);
        Tu[0] = cvt2(tv0.x, tv0.y); Tu[1] = cvt2(tv0.z, tv0.w);
        Tu[2] = cvt2(tv1.x, tv1.y); Tu[3] = cvt2(tv1.z, tv1.w);
        Uu[0] = cvt2(u0, u1); Uu[1] = cvt2(u2, u3);
        Uu[2] = cvt2(u4, u5); Uu[3] = cvt2(u6, u7);
        Vu[0] = cvt2(v0, v1); Vu[1] = cvt2(v2, v3);
        Vu[2] = cvt2(v4, v5); Vu[3] = cvt2(v6, v7);
        F[0] = Pu; F[1] = Tu; F[2] = Uu; F[3] = Vu;
    };

    // ---- h-blur MFMA from register fragments; pack D rows to uint2 ----
    auto hcompute = [&](const u32x4_t* F, uint2* dpk) {
#pragma unroll
        for (int q = 0; q < 4; ++q) {
            f32x4_t z = {0.f, 0.f, 0.f, 0.f};
            f32x4_t d = __builtin_amdgcn_mfma_f32_16x16x32_f16(
                __builtin_bit_cast(half8_t, F[q]), Bh, z, 0, 0, 0);
            dpk[q].x = cvt2(d[0], d[1]);
            dpk[q].y = cvt2(d[2], d[3]);
        }
    };
    // lane's 4 D rows (slots s0..s0+3, s0 mult of 4) = one 8B ds_write_b64
    auto hstore = [&](const uint2* dpk, int relbase) {
        int s0 = relbase + 4 * g4;
        if (s0 >= 96) s0 -= 96; else if (s0 >= 48) s0 -= 48;
#pragma unroll
        for (int q = 0; q < 4; ++q)
            *(uint2*)&s_ring[q][colA][s0] = dpk[q];
    };

    float lsum = 0.f;

    // ---- v-blur MFMA + SSIM. Reads rel 16j..16j+31 (k>=26 zero-weight;
    // all slots finite: wave-private zero-init or this wave's data). ----
    auto vblur = [&](int jstep) {
        int sg = 16 * jstep + (g4 << 3);
        if (sg >= 96) sg -= 96; else if (sg >= 48) sg -= 48;
        f32x4_t acc[4];
#pragma unroll
        for (int q = 0; q < 4; ++q) {
            u32x4_t ra = *(const u32x4_t*)&s_ring[q][colA][sg];
            f32x4_t z = {0.f, 0.f, 0.f, 0.f};
            acc[q] = __builtin_amdgcn_mfma_f32_16x16x32_f16(
                __builtin_bit_cast(half8_t, ra), Bv, z, 0, 0, 0);
        }
#pragma unroll
        for (int r = 0; r < 4; ++r) {
            float mp = acc[0][r], mt = acc[1][r];       // scaled by a
            float U  = acc[2][r], V  = acc[3][r];
            float mpt  = mp * mt;                        // a^2 * true
            float B2   = fmaf(mp, mp, mt * mt);          // a^2 * true
            float S    = fmaf(a, V, -mpt);               // a^2 * sigma_pt
            float Ssum = fmaf(a, U, -B2);                // a^2 * (sp+st)
            float num = fmaf(2.f, mpt, C1A) * fmaf(2.f, S, C2A);
            float den = (B2 + C1A) * (Ssum + C2A);
            lsum += __fdividef(num, den);
        }
    };

    // ---- Prologue (all wave-local; no barriers) ----
    float4 rp0, rp1, rt0, rt1;      // loop-carried raw set
    float4 sp0, sp1, st0, st1;      // prologue-only second set
    load8(y0 - 5, rp0, rp1, rt0, rt1);    // gen -2: rel 0..15
    load8(y0 + 7, sp0, sp1, st0, st1);    // gen -1: rel 12..27
    {
        // zero own wave's 16 columns: lane (g4,r15) zeros s_ring[g4][colA][*]
        u32x4_t z4 = {0u, 0u, 0u, 0u};
#pragma unroll
        for (int i = 0; i < 7; ++i)
            *(u32x4_t*)((char*)&s_ring[g4][colA][0] + i * 16) = z4;
    }
    u32x4_t F2[4], F1[4];
    uint2 d2[4], d1[4];
    make_frags(y0 - 5, rp0, rp1, rt0, rt1, F2);
    hcompute(F2, d2);
    make_frags(y0 + 7, sp0, sp1, st0, st1, F1);
    hcompute(F1, d1);
    load8(y0 + 23, rp0, rp1, rt0, rt1);   // gen 0 raw
    hstore(d2, 0);                         // rel 0..15 (after own-col zero)
    hstore(d1, 12);                        // rel 12..27 (12..15 same values)

    // ---- Main loop: 8 steps x 16 output rows, NO barriers ----
#pragma unroll 1
    for (int j = 0; j < 8; ++j) {
        u32x4_t F[4];
        uint2 dpk[4];
        if (j < 7) make_frags(y0 + 16 * j + 23, rp0, rp1, rt0, rt1, F);
        if (j < 6) load8(y0 + 16 * (j + 1) + 23, rp0, rp1, rt0, rt1);
        if (j < 7) {
            hcompute(F, dpk);
            hstore(dpk, 16 * j + 28);      // rel 16j+28..43 (own columns)
        }
        vblur(j);                          // reads rel 16j..16j+31 (own cols)
    }

    // ---- Block reduction -> one partial per block (the ONLY barrier) ----
#pragma unroll
    for (int off = 32; off > 0; off >>= 1) lsum += __shfl_down(lsum, off);
    if ((tid & 63) == 0) s_red[tid >> 6] = lsum;
    __syncthreads();
    if (tid == 0) {
        partial[(blockIdx.z * TILES_Y + blockIdx.y) * TILES_X + blockIdx.x] =
            s_red[0] + s_red[1] + s_red[2] + s_red[3];
    }
}

__global__ __launch_bounds__(256)
void ssim_final(const float* __restrict__ partial, float* __restrict__ out) {
    __shared__ float s_red[4];
    float s = 0.f;
    for (int i = threadIdx.x; i < NBLK; i += 256) s += partial[i];
#pragma unroll
    for (int off = 32; off > 0; off >>= 1) s += __shfl_down(s, off);
    if ((threadIdx.x & 63) == 0) s_red[threadIdx.x >> 6] = s;
    __syncthreads();
    if (threadIdx.x == 0) {
        float total = s_red[0] + s_red[1] + s_red[2] + s_red[3];
        out[0] = 1.0f - total / NPIXF;
    }
}

extern "C" void kernel_launch(void* const* d_in, const int* in_sizes, int n_in,
                              void* d_out, int out_size, void* d_ws, size_t ws_size,
                              hipStream_t stream) {
    const float* pred = (const float*)d_in[0];
    const float* tgt  = (const float*)d_in[1];
    float* partial = (float*)d_ws;   // NBLK floats, fully rewritten each call

    dim3 grid(TILES_X, TILES_Y, PLANES);
    ssim_main<<<grid, dim3(256), 0, stream>>>(pred, tgt, partial);
    ssim_final<<<1, dim3(256), 0, stream>>>(partial, (float*)d_out);
}